// Round 10
// baseline (565.614 us; speedup 1.0000x reference)
//
#include <hip/hip_runtime.h>

// Problem constants
#define BB        16
#define HH        6
#define WW        4096
#define CC        128
#define TT        1024          // W/OVERLAP
#define NTOK      16384         // B*T
#define FIX       768           // H*C
#define HID       1024
#define CBK       1024
#define CBD       8
#define NPVQ      3
#define NRVQ      6
#define ZQ_SIZE   50331648ull   // B*H*W*C

// ws layout (byte offsets), all 16-aligned
#define OFF_ACC   0ull                            // 16 B loss accumulator (double)
#define OFF_EN64  16ull                           // 18*1024*8 f64 = 1179648 B
#define OFF_EN32  (OFF_EN64 + 1179648ull)         // 18*1024*8 f32 = 589824 B
#define OFF_PUT   (OFF_EN32 + 589824ull)          // 3*1024*8 f32  = 98304 B
#define OFF_R     (OFF_PUT + 98304ull)            // 3*16384*8 f64 = 3145728 B
#define OFF_ZQ    (OFF_R + 3145728ull)            // 3*16384*8 f32 = 1572864 B

typedef float v2f __attribute__((ext_vector_type(2)));

// fp32 dot, 8 elems. Packed lo/hi chains: acc.x <- d0,d2,d4,d6 ;
// acc.y <- d1,d3,d5,d7 ; identical op order to R7/R8 -> bit-identical dots.
__device__ __forceinline__ float dot32v(const float4 e0, const float4 e1,
                                        const v2f rn2[4]) {
    v2f acc = {0.0f, 0.0f};
    v2f p;
    p.x = e0.x; p.y = e0.y; acc = __builtin_elementwise_fma(rn2[0], p, acc);
    p.x = e0.z; p.y = e0.w; acc = __builtin_elementwise_fma(rn2[1], p, acc);
    p.x = e1.x; p.y = e1.y; acc = __builtin_elementwise_fma(rn2[2], p, acc);
    p.x = e1.z; p.y = e1.w; acc = __builtin_elementwise_fma(rn2[3], p, acc);
    return acc.x + acc.y;
}

// ---------------------------------------------------------------------------
// Kernel A1: l2-normalize all 18 codebooks -> fp64 table + fp32 mirror
// ---------------------------------------------------------------------------
__global__ __launch_bounds__(256) void knorm(const float* __restrict__ emb,
                                             double* __restrict__ en64,
                                             float* __restrict__ en32) {
    int gid = blockIdx.x * 256 + threadIdx.x;
    if (gid >= NPVQ * NRVQ * CBK) return;
    const float* e = emb + (size_t)gid * CBD;
    double v[CBD];
    double s = 0.0;
#pragma unroll
    for (int d = 0; d < CBD; ++d) { v[d] = (double)e[d]; s += v[d] * v[d]; }
    double n = fmax(sqrt(s), 1e-12);
#pragma unroll
    for (int d = 0; d < CBD; ++d) {
        double q = v[d] / n;
        en64[(size_t)gid * CBD + d] = q;
        en32[(size_t)gid * CBD + d] = (float)q;
    }
}

// ---------------------------------------------------------------------------
// Kernel A2: transpose pu[m][d][j] -> pu_t[m][j][d]  (96 KB, one-time)
// ---------------------------------------------------------------------------
__global__ __launch_bounds__(256) void kputr(const float* __restrict__ pu,
                                             float* __restrict__ pu_t) {
    int gid = blockIdx.x * 256 + threadIdx.x;        // coalesced read of pu
    if (gid >= NPVQ * CBD * HID) return;
    int j = gid & (HID - 1), md = gid >> 10;
    int m = md >> 3, d = md & 7;
    pu_t[((size_t)m * HID + j) * CBD + d] = pu[gid];
}

// ---------------------------------------------------------------------------
// Kernel B: gather 2 tokens (24 KB) into LDS, project 1024->8 (fp64).
// 384 thr = 6 waves: wave w -> token (w>=3), m = w%3. (R5 index fix kept.)
// ---------------------------------------------------------------------------
__global__ __launch_bounds__(384) void kproj(const float* __restrict__ ze,
                                             const float* __restrict__ pd,
                                             double* __restrict__ r_ws) {
    __shared__ float x[2][NPVQ * HID];   // 24 KB
    const int tok0 = blockIdx.x * 2;
    const int b = tok0 >> 10, t0 = tok0 & 1023;
    const int tid = threadIdx.x;
    const size_t zbase = (size_t)b * (HH * WW * CC);
#pragma unroll
    for (int q = 0; q < 4; ++q) {
        int g = tid + 384 * q;                 // [0,1536)
        int tk = g >= 768;
        int gg = g - tk * 768;                 // (768 not pow2 — no masking!)
        int h = gg >> 7, v = gg & 127;
        const float4 val = *(const float4*)(ze + zbase + (size_t)(h * WW + (t0 + tk) * 4) * CC + v * 4);
        float vv[4] = {val.x, val.y, val.z, val.w};
#pragma unroll
        for (int e = 0; e < 4; ++e) {
            int oc = v * 4 + e, o = oc >> 7, c = oc & 127;
            x[tk][o * FIX + c * HH + h] = vv[e];
        }
    }
    __syncthreads();
    const int w = tid >> 6, l = tid & 63;
    const int tk = w >= 3, m = w - tk * 3;
    double acc[CBD] = {0, 0, 0, 0, 0, 0, 0, 0};
    for (int q = 0; q < 16; ++q) {
        int j = l + 64 * q;
        double xv = (double)x[tk][m * HID + j];
        const float* pr = pd + (size_t)(m * HID + j) * CBD;
#pragma unroll
        for (int d = 0; d < CBD; ++d) acc[d] = fma(xv, (double)pr[d], acc[d]);
    }
#pragma unroll
    for (int off = 32; off >= 1; off >>= 1) {
#pragma unroll
        for (int d = 0; d < CBD; ++d) acc[d] += __shfl_down(acc[d], off, 64);
    }
    if (l == 0) {
        double* rp = r_ws + ((size_t)m * NTOK + tok0 + tk) * CBD;
#pragma unroll
        for (int d = 0; d < CBD; ++d) rp[d] = acc[d];
    }
}

// ---------------------------------------------------------------------------
// Kernel C: residual VQ, register-stationary codebook. 1-wave blocks, grid
// = 3m x 256 groups = 768 blocks (3 waves/CU on separate SIMDs). Lane l owns
// token g*64+l AND codes {c*64+l, c=0..15} in 128 VGPRs (coalesced load).
// Per token: broadcast rn via 2KB LDS, each lane scans its 16 register codes
// (ZERO LDS in hot loop), value-only top-2 shfl_xor butterfly + ballot index
// resolve. fp32 value-ties => gap<=EPS => fp64 recert with explicit global-
// index tie-break, so first-occurrence argmin semantics are preserved;
// non-tied decisions are value-identical to R7/R8 (same dot32v, rn2, EPS).
// ---------------------------------------------------------------------------
#define KV_EPS      2e-6f              // cert gap  (> 2x fp32 8-dot err bound)
#define KV_EPS_CAND 2e-6f              // candidate window (same 2e bound)

__global__ __launch_bounds__(64) void kvq(const double* __restrict__ en_all,
                                          const float* __restrict__ es_all,
                                          const double* __restrict__ r_ws,
                                          float* __restrict__ zq_ws,
                                          float* __restrict__ out,     // d_out base
                                          const int* __restrict__ nsp,
                                          double* __restrict__ accum) {
    __shared__ __align__(16) float  rn_sh[64][CBD];   // 2 KB (fp32 broadcast)
    __shared__ __align__(16) double rd_sh[64][CBD];   // 4 KB (fp64, recert only)

    const int blk = blockIdx.x;        // [0, 768)
    const int m = blk >> 8, g = blk & 255;
    const int l = threadIdx.x;
    const int tok = g * 64 + l;
    const int b = tok >> 10, t = tok & 1023;
    const int ns = *nsp;

    double r[CBD];
    {
        const double* rp = r_ws + ((size_t)m * NTOK + tok) * CBD;
#pragma unroll
        for (int d = 0; d < CBD; ++d) r[d] = rp[d];
    }
    float zq[CBD];
#pragma unroll
    for (int d = 0; d < CBD; ++d) zq[d] = 0.0f;
    double loss = 0.0;

    for (int i = 0; i < ns; ++i) {
        const double* en = en_all + ((size_t)(m * NRVQ + i)) * CBK * CBD;
        const float*  es = es_all + ((size_t)(m * NRVQ + i)) * CBK * CBD;

        // rn = fp64-normalized residual, cast fp32 (identical to R7/R8)
        double s = 0.0;
#pragma unroll
        for (int d = 0; d < CBD; ++d) s += r[d] * r[d];
        double inv = 1.0 / fmax(sqrt(s), 1e-12);
        float rn[CBD];
#pragma unroll
        for (int d = 0; d < CBD; ++d) rn[d] = (float)(r[d] * inv);

        __syncthreads();   // rn_sh/rd_sh free (prev stream readers done)
        *(float4*)&rn_sh[l][0] = make_float4(rn[0], rn[1], rn[2], rn[3]);
        *(float4*)&rn_sh[l][4] = make_float4(rn[4], rn[5], rn[6], rn[7]);

        // codebook -> registers: lane l holds codes k = c*64 + l.
        // float4 index of code k, half h: k*2+h = c*128 + l*2 + h -> lanes
        // read stride-32B = coalesced pairs.
        float4 cb[32];
        {
            const float4* src = (const float4*)es;
#pragma unroll
            for (int c = 0; c < 16; ++c) {
                cb[2 * c]     = src[c * 128 + l * 2];
                cb[2 * c + 1] = src[c * 128 + l * 2 + 1];
            }
        }
        __syncthreads();   // rn_sh ready

        float myB1 = 0.0f;
        int   myK  = 0;
        bool  myUnc = false;

#pragma unroll 2
        for (int j = 0; j < 64; ++j) {
            // broadcast token j's rn (uniform-address LDS read, conflict-free)
            float4 ra = *(const float4*)&rn_sh[j][0];
            float4 rb4 = *(const float4*)&rn_sh[j][4];
            v2f rB[4];
            rB[0].x = ra.x;  rB[0].y = ra.y;
            rB[1].x = ra.z;  rB[1].y = ra.w;
            rB[2].x = rb4.x; rB[2].y = rb4.y;
            rB[3].x = rb4.z; rB[3].y = rb4.w;

            float b1 = -1e30f, b2 = -1e30f;
            int bk = l;
#pragma unroll
            for (int c = 0; c < 16; ++c) {
                float dv = dot32v(cb[2 * c], cb[2 * c + 1], rB);
                // ascending global idx within lane (k = c*64+l, c ascending)
                if (dv > b1) { b2 = b1; b1 = dv; bk = c * 64 + l; }
                else if (dv > b2) { b2 = dv; }
            }
            // value-only top-2 butterfly across 64 lanes (exact top-2 of union;
            // any cross-lane tie collapses gap to 0 -> unc -> fp64 recert)
            float g1 = b1, g2 = b2;
#pragma unroll
            for (int mask = 1; mask < 64; mask <<= 1) {
                float o1 = __shfl_xor(g1, mask, 64);
                float o2 = __shfl_xor(g2, mask, 64);
                float hi = fmaxf(g1, o1);
                float lo = fminf(g1, o1);
                g2 = fmaxf(fmaxf(g2, o2), lo);
                g1 = hi;
            }
            // index resolve: unique max (non-tie) -> exactly one lane matches
            unsigned long long mk = __ballot(b1 == g1);
            int src = __ffsll(mk) - 1;
            int K = __shfl(bk, src, 64);
            bool uj = (g1 - g2) <= KV_EPS;
            if (l == j) { myB1 = g1; myK = K; myUnc = uj; }
        }

        // targeted fp64 re-certification (rare; wave-uniform control flow)
        unsigned long long um = __ballot(myUnc);
        if (um) {
            *(double2*)&rd_sh[l][0] = make_double2(r[0], r[1]);
            *(double2*)&rd_sh[l][2] = make_double2(r[2], r[3]);
            *(double2*)&rd_sh[l][4] = make_double2(r[4], r[5]);
            *(double2*)&rd_sh[l][6] = make_double2(r[6], r[7]);
            __syncthreads();
            while (um) {
                int j = __ffsll(um) - 1;
                um &= um - 1;
                float B1j = __shfl(myB1, j, 64);
                float4 ra = *(const float4*)&rn_sh[j][0];
                float4 rb4 = *(const float4*)&rn_sh[j][4];
                v2f rB[4];
                rB[0].x = ra.x;  rB[0].y = ra.y;
                rB[1].x = ra.z;  rB[1].y = ra.w;
                rB[2].x = rb4.x; rB[2].y = rb4.y;
                rB[3].x = rb4.z; rB[3].y = rb4.w;
                double rj[CBD];
#pragma unroll
                for (int d = 0; d < CBD; ++d) rj[d] = rd_sh[j][d];
                double rb = -1e300;
                int rk = CBK;    // sentinel
#pragma unroll
                for (int c = 0; c < 16; ++c) {
                    float dv = dot32v(cb[2 * c], cb[2 * c + 1], rB);  // identical recompute
                    int kk = c * 64 + l;
                    if (dv >= B1j - KV_EPS_CAND) {
                        const double* e64 = en + (size_t)kk * CBD;
                        double q0 = 0.0, q1 = 0.0;
#pragma unroll
                        for (int d = 0; d < CBD; d += 2) {
                            q0 = fma(rj[d], e64[d], q0);
                            q1 = fma(rj[d + 1], e64[d + 1], q1);
                        }
                        double dot = q0 + q1;
                        if (dot > rb || (dot == rb && kk < rk)) { rb = dot; rk = kk; }
                    }
                }
                // fp64 (value, min-global-idx) butterfly
#pragma unroll
                for (int mask = 1; mask < 64; mask <<= 1) {
                    double ov = __shfl_xor(rb, mask, 64);
                    int    ok = __shfl_xor(rk, mask, 64);
                    bool take = (ov > rb) || (ov == rb && ok < rk);
                    rb = take ? ov : rb;
                    rk = take ? ok : rk;
                }
                if (l == j) myK = rk;
            }
        }

        // winner gather (L2-resident fp64) + exact updates, all lanes parallel
        const double* qv = en + (size_t)myK * CBD;
        double ls = 0.0;
#pragma unroll
        for (int d = 0; d < CBD; ++d) {
            double q = qv[d];
            double df = q - r[d];
            ls += df * df;
            r[d] -= q;
            zq[d] += (float)q;
        }
        loss += ls;
        out[ZQ_SIZE + ((size_t)(b * ns + i) * NPVQ + m) * TT + t] = (float)myK;
    }

    {
        float* zp = zq_ws + ((size_t)m * NTOK + tok) * CBD;
        *(float4*)&zp[0] = make_float4(zq[0], zq[1], zq[2], zq[3]);
        *(float4*)&zp[4] = make_float4(zq[4], zq[5], zq[6], zq[7]);
    }
#pragma unroll
    for (int off = 32; off >= 1; off >>= 1) loss += __shfl_down(loss, off, 64);
    if (l == 0) atomicAdd(accum, loss);
}

// ---------------------------------------------------------------------------
// Kernel D: up-projection 8->1024 + inverse permutation scatter (coalesced),
// plus loss epilogue. Block = 32 consecutive tokens.
// ---------------------------------------------------------------------------
__global__ __launch_bounds__(256) void kout(const float* __restrict__ pu_t,
                                            const float* __restrict__ zq_ws,
                                            float* __restrict__ out,
                                            const int* __restrict__ nsp,
                                            const double* __restrict__ accum) {
    __shared__ float zl[32][NPVQ][CBD];   // 3 KB
    const int blk = blockIdx.x;
    const int tok0 = blk * 32;
    const int b = tok0 >> 10, t0 = tok0 & 1023;
    const int tid = threadIdx.x;
#pragma unroll
    for (int q = 0; q < 3; ++q) {
        int ii = tid + 256 * q;            // [0,768)
        int mm = ii >> 8, rem = ii & 255, tt = rem >> 3, d = rem & 7;
        zl[tt][mm][d] = zq_ws[((size_t)mm * NTOK + tok0 + tt) * CBD + d];
    }
    __syncthreads();
    const size_t obase = (size_t)b * (HH * WW * CC);
#pragma unroll 2
    for (int q = 0; q < 12; ++q) {
        int idx = tid + 256 * q;           // (h,o,c) linear
        int h = idx >> 9, rem = idx & 511, o = rem >> 7, c = rem & 127;
        int f = o * FIX + c * HH + h;
        int m = f >> 10, j = f & 1023;
        const float4* p4 = (const float4*)(pu_t + ((size_t)m * HID + j) * CBD);
        float4 pa = p4[0], pb = p4[1];
        float pu8[CBD] = {pa.x, pa.y, pa.z, pa.w, pb.x, pb.y, pb.z, pb.w};
        size_t rowbase = obase + ((size_t)h * WW + t0 * 4 + o) * CC + c;
        for (int tt = 0; tt < 32; ++tt) {
            float y = 0.0f;
#pragma unroll
            for (int d = 0; d < CBD; ++d) y = fmaf(zl[tt][m][d], pu8[d], y);
            out[rowbase + (size_t)tt * 4 * CC] = y;
        }
    }
    if (blk == 0 && tid == 0) {
        int ns = *nsp;
        double s = *accum;
        float lv = (float)(s / (double)(NTOK * CBD * NPVQ));
        size_t lbase = ZQ_SIZE + (size_t)BB * ns * NPVQ * TT;
        out[lbase] = lv;       // cb_loss / 3
        out[lbase + 1] = lv;   // cm_loss / 3 (numerically identical)
    }
}

// ---------------------------------------------------------------------------
extern "C" void kernel_launch(void* const* d_in, const int* in_sizes, int n_in,
                              void* d_out, int out_size, void* d_ws, size_t ws_size,
                              hipStream_t stream) {
    const float* ze  = (const float*)d_in[0];
    const float* emb = (const float*)d_in[1];
    const float* pd  = (const float*)d_in[2];
    const float* pu  = (const float*)d_in[3];
    const int*   nsp = (const int*)d_in[4];
    float* out = (float*)d_out;
    char* ws = (char*)d_ws;

    double* accum = (double*)(ws + OFF_ACC);
    double* en64  = (double*)(ws + OFF_EN64);
    float*  en32  = (float*)(ws + OFF_EN32);
    float*  pu_t  = (float*)(ws + OFF_PUT);
    double* r_ws  = (double*)(ws + OFF_R);
    float*  zq_ws = (float*)(ws + OFF_ZQ);

    hipMemsetAsync(accum, 0, 16, stream);
    knorm<<<(NPVQ * NRVQ * CBK + 255) / 256, 256, 0, stream>>>(emb, en64, en32);
    kputr<<<(NPVQ * CBD * HID + 255) / 256, 256, 0, stream>>>(pu, pu_t);
    kproj<<<NTOK / 2, 384, 0, stream>>>(ze, pd, r_ws);
    kvq<<<NPVQ * (NTOK / 64), 64, 0, stream>>>(en64, en32, r_ws, zq_ws, out, nsp, accum);
    kout<<<NTOK / 32, 256, 0, stream>>>(pu_t, zq_ws, out, nsp, accum);
}

// Round 11
// 484.240 us; speedup vs baseline: 1.1680x; 1.1680x over previous
//
#include <hip/hip_runtime.h>

// Problem constants
#define BB        16
#define HH        6
#define WW        4096
#define CC        128
#define TT        1024          // W/OVERLAP
#define NTOK      16384         // B*T
#define FIX       768           // H*C
#define HID       1024
#define CBK       1024
#define CBD       8
#define NPVQ      3
#define NRVQ      6
#define ZQ_SIZE   50331648ull   // B*H*W*C

// ws layout (byte offsets), all 16-aligned
#define OFF_ACC   0ull                            // 16 B loss accumulator (double)
#define OFF_EN64  16ull                           // 18*1024*8 f64 = 1179648 B
#define OFF_EN32  (OFF_EN64 + 1179648ull)         // 18*1024*8 f32 = 589824 B
#define OFF_PUT   (OFF_EN32 + 589824ull)          // 3*1024*8 f32  = 98304 B
#define OFF_R     (OFF_PUT + 98304ull)            // 3*16384*8 f64 = 3145728 B
#define OFF_ZQ    (OFF_R + 3145728ull)            // 3*16384*8 f32 = 1572864 B

typedef float v2f __attribute__((ext_vector_type(2)));

// fp32 dot, 8 elems, from pre-loaded float4 pair. Packed lo/hi chains:
// acc.x <- d0,d2,d4,d6 ; acc.y <- d1,d3,d5,d7 ; same order as R7/R8 ->
// bit-identical dot values; v_pk_fma_f32 halves VALU issue.
__device__ __forceinline__ float dot32v(const float4 e0, const float4 e1,
                                        const v2f rn2[4]) {
    v2f acc = {0.0f, 0.0f};
    v2f p;
    p.x = e0.x; p.y = e0.y; acc = __builtin_elementwise_fma(rn2[0], p, acc);
    p.x = e0.z; p.y = e0.w; acc = __builtin_elementwise_fma(rn2[1], p, acc);
    p.x = e1.x; p.y = e1.y; acc = __builtin_elementwise_fma(rn2[2], p, acc);
    p.x = e1.z; p.y = e1.w; acc = __builtin_elementwise_fma(rn2[3], p, acc);
    return acc.x + acc.y;
}

// ---------------------------------------------------------------------------
// Kernel A1: l2-normalize all 18 codebooks -> fp64 table + fp32 mirror
// ---------------------------------------------------------------------------
__global__ __launch_bounds__(256) void knorm(const float* __restrict__ emb,
                                             double* __restrict__ en64,
                                             float* __restrict__ en32) {
    int gid = blockIdx.x * 256 + threadIdx.x;
    if (gid >= NPVQ * NRVQ * CBK) return;
    const float* e = emb + (size_t)gid * CBD;
    double v[CBD];
    double s = 0.0;
#pragma unroll
    for (int d = 0; d < CBD; ++d) { v[d] = (double)e[d]; s += v[d] * v[d]; }
    double n = fmax(sqrt(s), 1e-12);
#pragma unroll
    for (int d = 0; d < CBD; ++d) {
        double q = v[d] / n;
        en64[(size_t)gid * CBD + d] = q;
        en32[(size_t)gid * CBD + d] = (float)q;
    }
}

// ---------------------------------------------------------------------------
// Kernel A2: transpose pu[m][d][j] -> pu_t[m][j][d]  (96 KB, one-time)
// ---------------------------------------------------------------------------
__global__ __launch_bounds__(256) void kputr(const float* __restrict__ pu,
                                             float* __restrict__ pu_t) {
    int gid = blockIdx.x * 256 + threadIdx.x;        // coalesced read of pu
    if (gid >= NPVQ * CBD * HID) return;
    int j = gid & (HID - 1), md = gid >> 10;
    int m = md >> 3, d = md & 7;
    pu_t[((size_t)m * HID + j) * CBD + d] = pu[gid];
}

// ---------------------------------------------------------------------------
// Kernel B: gather 2 tokens (24 KB) into LDS, project 1024->8 (fp64).
// 384 thr = 6 waves: wave w -> token (w>=3), m = w%3. (R5 index fix kept.)
// ---------------------------------------------------------------------------
__global__ __launch_bounds__(384) void kproj(const float* __restrict__ ze,
                                             const float* __restrict__ pd,
                                             double* __restrict__ r_ws) {
    __shared__ float x[2][NPVQ * HID];   // 24 KB
    const int tok0 = blockIdx.x * 2;
    const int b = tok0 >> 10, t0 = tok0 & 1023;
    const int tid = threadIdx.x;
    const size_t zbase = (size_t)b * (HH * WW * CC);
#pragma unroll
    for (int q = 0; q < 4; ++q) {
        int g = tid + 384 * q;                 // [0,1536)
        int tk = g >= 768;
        int gg = g - tk * 768;                 // (768 not pow2 — no masking!)
        int h = gg >> 7, v = gg & 127;
        const float4 val = *(const float4*)(ze + zbase + (size_t)(h * WW + (t0 + tk) * 4) * CC + v * 4);
        float vv[4] = {val.x, val.y, val.z, val.w};
#pragma unroll
        for (int e = 0; e < 4; ++e) {
            int oc = v * 4 + e, o = oc >> 7, c = oc & 127;
            x[tk][o * FIX + c * HH + h] = vv[e];
        }
    }
    __syncthreads();
    const int w = tid >> 6, l = tid & 63;
    const int tk = w >= 3, m = w - tk * 3;
    double acc[CBD] = {0, 0, 0, 0, 0, 0, 0, 0};
    for (int q = 0; q < 16; ++q) {
        int j = l + 64 * q;
        double xv = (double)x[tk][m * HID + j];
        const float* pr = pd + (size_t)(m * HID + j) * CBD;
#pragma unroll
        for (int d = 0; d < CBD; ++d) acc[d] = fma(xv, (double)pr[d], acc[d]);
    }
#pragma unroll
    for (int off = 32; off >= 1; off >>= 1) {
#pragma unroll
        for (int d = 0; d < CBD; ++d) acc[d] += __shfl_down(acc[d], off, 64);
    }
    if (l == 0) {
        double* rp = r_ws + ((size_t)m * NTOK + tok0 + tk) * CBD;
#pragma unroll
        for (int d = 0; d < CBD; ++d) rp[d] = acc[d];
    }
}

// ---------------------------------------------------------------------------
// Kernel C: residual VQ. fp32 certified scan + targeted fp64 recert.
// R11: T=2 tokens per lane (128 tokens/block, 384 blocks = 1.5/CU).
// Rationale: scan reads/CU = 2048 x block-streams/CU, so T=2 halves the
// saturated LDS-pipe traffic (R8 wall) while keeping loaded CUs at 16
// waves (4/SIMD) -- the proven throughput regime. R9 (T=4, 0.75 blk/CU,
// 8 waves) and R10 (1-wave blocks) both starved latency-hiding; T=2 is
// the middle point. Logic is R9's (correctness-proven), only KV_T/grid
// changed. Per-token decisions bit-identical to R7/R8.
// ---------------------------------------------------------------------------
#define KV_WAVES    8
#define KV_THREADS  (KV_WAVES * 64)
#define KV_T        2                  // tokens per lane
#define KV_TPB      (64 * KV_T)        // 128 tokens per block
#define KV_WSLICE   (CBK / KV_WAVES)   // 128
#define KV_EPS      2e-6f              // cert gap  (> 2x fp32 8-dot err bound)
#define KV_EPS_CAND 2e-6f              // candidate window (same 2e bound)

__global__ __launch_bounds__(KV_THREADS, 2) void kvq(const double* __restrict__ en_all,
                                                     const float* __restrict__ es_all,
                                                     const double* __restrict__ r_ws,
                                                     float* __restrict__ zq_ws,
                                                     float* __restrict__ out,   // d_out base
                                                     const int* __restrict__ nsp,
                                                     double* __restrict__ accum) {
    __shared__ __align__(16) float tbl[CBK * CBD];   // 32 KB
    __shared__ float  mb1[KV_T][KV_THREADS];         // 4 KB
    __shared__ float  mb2[KV_T][KV_THREADS];         // 4 KB
    __shared__ int    mbk[KV_T][KV_THREADS];         // 4 KB
    __shared__ double md64[KV_THREADS];              // 4 KB (recert, reused per j)
    __shared__ int    mk64[KV_THREADS];              // 2 KB

    const int blk = blockIdx.x;        // [0, 384)
    const int m = blk / (NTOK / KV_TPB), gg = blk % (NTOK / KV_TPB);
    const int tid = threadIdx.x;
    const int w = tid >> 6, l = tid & 63;
    const int ns = *nsp;

    double r[KV_T][CBD];
#pragma unroll
    for (int j = 0; j < KV_T; ++j) {
        const int tok = gg * KV_TPB + j * 64 + l;
        const double* rp = r_ws + ((size_t)m * NTOK + tok) * CBD;
#pragma unroll
        for (int d = 0; d < CBD; ++d) r[j][d] = rp[d];
    }
    float zq[KV_T][CBD];
#pragma unroll
    for (int j = 0; j < KV_T; ++j)
#pragma unroll
        for (int d = 0; d < CBD; ++d) zq[j][d] = 0.0f;
    double loss = 0.0;

    const int kl0 = w * KV_WSLICE;
    for (int i = 0; i < ns; ++i) {
        const double* en = en_all + ((size_t)(m * NRVQ + i)) * CBK * CBD;
        const float*  es = es_all + ((size_t)(m * NRVQ + i)) * CBK * CBD;
        // rn = fp64-normalized residual, cast fp32 (scan is scale-invariant)
        v2f rn2[KV_T][4];
#pragma unroll
        for (int j = 0; j < KV_T; ++j) {
            double s = 0.0;
#pragma unroll
            for (int d = 0; d < CBD; ++d) s += r[j][d] * r[j][d];
            double inv = 1.0 / fmax(sqrt(s), 1e-12);
#pragma unroll
            for (int d = 0; d < CBD; d += 2) {
                rn2[j][d >> 1].x = (float)(r[j][d] * inv);
                rn2[j][d >> 1].y = (float)(r[j][d + 1] * inv);
            }
        }

        __syncthreads();   // table + merge arrays free (prev stream done)
        {   // stage full fp32 codebook: 2048 float4, 4 per thread, coalesced
            const float4* src = (const float4*)es;
            float4* dst = (float4*)tbl;
#pragma unroll
            for (int q = 0; q < 4; ++q) dst[tid + KV_THREADS * q] = src[tid + KV_THREADS * q];
        }
        __syncthreads();   // table ready

        float b1[KV_T], b2[KV_T];
        int bk[KV_T];
#pragma unroll
        for (int j = 0; j < KV_T; ++j) { b1[j] = -1e30f; b2[j] = -1e30f; bk[j] = kl0; }
        for (int k = kl0; k < kl0 + KV_WSLICE; k += 2) {
            const float4* pA = (const float4*)(tbl + (size_t)k * CBD);
            float4 a0 = pA[0], a1 = pA[1];       // code k
            float4 c0 = pA[2], c1 = pA[3];       // code k+1
#pragma unroll
            for (int j = 0; j < KV_T; ++j) {
                float dA = dot32v(a0, a1, rn2[j]);
                float dB = dot32v(c0, c1, rn2[j]);
                // ascending k, strict >: first max (== np.argmin on dist)
                if (dA > b1[j]) { b2[j] = b1[j]; b1[j] = dA; bk[j] = k; }
                else if (dA > b2[j]) { b2[j] = dA; }
                if (dB > b1[j]) { b2[j] = b1[j]; b1[j] = dB; bk[j] = k + 1; }
                else if (dB > b2[j]) { b2[j] = dB; }
            }
        }
#pragma unroll
        for (int j = 0; j < KV_T; ++j) {
            mb1[j][tid] = b1[j]; mb2[j][tid] = b2[j]; mbk[j][tid] = bk[j];
        }
        __syncthreads();
        // 8-way top-2 merge per sub-token (slices ascending in w)
        float B1[KV_T], B2[KV_T];
        int bbk[KV_T];
        bool unc[KV_T];
        bool anyu = false;
#pragma unroll
        for (int j = 0; j < KV_T; ++j) {
            float x1 = mb1[j][l], x2 = mb2[j][l];
            int xk = mbk[j][l];
#pragma unroll
            for (int w2 = 1; w2 < KV_WAVES; ++w2) {
                float c1 = mb1[j][w2 * 64 + l];
                float c2 = mb2[j][w2 * 64 + l];
                int   ck = mbk[j][w2 * 64 + l];
                if (c1 > x1) { x2 = fmaxf(x1, c2); x1 = c1; xk = ck; }
                else         { x2 = fmaxf(x2, c1); }
            }
            B1[j] = x1; B2[j] = x2; bbk[j] = xk;
            unc[j] = (x1 - x2) <= KV_EPS;
            anyu |= unc[j];
        }
        // every wave computes identical unc pattern for lane l => __any is
        // block-uniform => conditional barriers below are race-free.
        if (__any(anyu)) {
            double rb[KV_T];
            int rk[KV_T];
#pragma unroll
            for (int j = 0; j < KV_T; ++j) { rb[j] = -1e300; rk[j] = CBK; }
            for (int k = kl0; k < kl0 + KV_WSLICE; ++k) {
                const float4* pA = (const float4*)(tbl + (size_t)k * CBD);
                float4 e0 = pA[0], e1 = pA[1];
#pragma unroll
                for (int j = 0; j < KV_T; ++j) {
                    float dv = dot32v(e0, e1, rn2[j]);   // identical recompute
                    if (unc[j] && dv >= B1[j] - KV_EPS_CAND) {
                        const double* e64 = en + (size_t)k * CBD;
                        double q0 = 0.0, q1 = 0.0;
#pragma unroll
                        for (int d = 0; d < CBD; d += 2) {
                            q0 = fma(r[j][d], e64[d], q0);
                            q1 = fma(r[j][d + 1], e64[d + 1], q1);
                        }
                        double dot = q0 + q1;
                        if (dot > rb[j] || (dot == rb[j] && k < rk[j])) { rb[j] = dot; rk[j] = k; }
                    }
                }
            }
            // sequential merges through one shared buffer (rare path)
            for (int j = 0; j < KV_T; ++j) {
                __syncthreads();   // buffer free (prev j merged)
                md64[tid] = rb[j]; mk64[tid] = rk[j];
                __syncthreads();
                if (unc[j]) {
                    double R = md64[l];
                    int RK = mk64[l];
#pragma unroll
                    for (int w2 = 1; w2 < KV_WAVES; ++w2) {
                        double d2 = md64[w2 * 64 + l];
                        int    k2 = mk64[w2 * 64 + l];
                        if (d2 > R || (d2 == R && k2 < RK)) { R = d2; RK = k2; }
                    }
                    bbk[j] = RK;
                }
            }
        }
        // winners in fp64 (L2-resident): exact residual update + loss
#pragma unroll
        for (int j = 0; j < KV_T; ++j) {
            const double* qv = en + (size_t)bbk[j] * CBD;
            if (w == 0) {
                double ls = 0.0;
#pragma unroll
                for (int d = 0; d < CBD; ++d) { double df = qv[d] - r[j][d]; ls += df * df; }
                loss += ls;
                const int tok = gg * KV_TPB + j * 64 + l;
                const int b = tok >> 10, t = tok & 1023;
                out[ZQ_SIZE + ((size_t)(b * ns + i) * NPVQ + m) * TT + t] = (float)bbk[j];
            }
#pragma unroll
            for (int d = 0; d < CBD; ++d) {
                double q = qv[d];
                r[j][d] -= q;
                zq[j][d] += (float)q;
            }
        }
    }

    if (w == 0) {
#pragma unroll
        for (int j = 0; j < KV_T; ++j) {
            const int tok = gg * KV_TPB + j * 64 + l;
            float* zp = zq_ws + ((size_t)m * NTOK + tok) * CBD;
#pragma unroll
            for (int d = 0; d < CBD; ++d) zp[d] = zq[j][d];
        }
#pragma unroll
        for (int off = 32; off >= 1; off >>= 1) loss += __shfl_down(loss, off, 64);
        if (l == 0) atomicAdd(accum, loss);
    }
}

// ---------------------------------------------------------------------------
// Kernel D: up-projection 8->1024 + inverse permutation scatter (coalesced),
// plus loss epilogue. Block = 32 consecutive tokens.
// ---------------------------------------------------------------------------
__global__ __launch_bounds__(256) void kout(const float* __restrict__ pu_t,
                                            const float* __restrict__ zq_ws,
                                            float* __restrict__ out,
                                            const int* __restrict__ nsp,
                                            const double* __restrict__ accum) {
    __shared__ float zl[32][NPVQ][CBD];   // 3 KB
    const int blk = blockIdx.x;
    const int tok0 = blk * 32;
    const int b = tok0 >> 10, t0 = tok0 & 1023;
    const int tid = threadIdx.x;
#pragma unroll
    for (int q = 0; q < 3; ++q) {
        int ii = tid + 256 * q;            // [0,768)
        int mm = ii >> 8, rem = ii & 255, tt = rem >> 3, d = rem & 7;
        zl[tt][mm][d] = zq_ws[((size_t)mm * NTOK + tok0 + tt) * CBD + d];
    }
    __syncthreads();
    const size_t obase = (size_t)b * (HH * WW * CC);
#pragma unroll 2
    for (int q = 0; q < 12; ++q) {
        int idx = tid + 256 * q;           // (h,o,c) linear
        int h = idx >> 9, rem = idx & 511, o = rem >> 7, c = rem & 127;
        int f = o * FIX + c * HH + h;
        int m = f >> 10, j = f & 1023;
        const float4* p4 = (const float4*)(pu_t + ((size_t)m * HID + j) * CBD);
        float4 pa = p4[0], pb = p4[1];
        float pu8[CBD] = {pa.x, pa.y, pa.z, pa.w, pb.x, pb.y, pb.z, pb.w};
        size_t rowbase = obase + ((size_t)h * WW + t0 * 4 + o) * CC + c;
        for (int tt = 0; tt < 32; ++tt) {
            float y = 0.0f;
#pragma unroll
            for (int d = 0; d < CBD; ++d) y = fmaf(zl[tt][m][d], pu8[d], y);
            out[rowbase + (size_t)tt * 4 * CC] = y;
        }
    }
    if (blk == 0 && tid == 0) {
        int ns = *nsp;
        double s = *accum;
        float lv = (float)(s / (double)(NTOK * CBD * NPVQ));
        size_t lbase = ZQ_SIZE + (size_t)BB * ns * NPVQ * TT;
        out[lbase] = lv;       // cb_loss / 3
        out[lbase + 1] = lv;   // cm_loss / 3 (numerically identical)
    }
}

// ---------------------------------------------------------------------------
extern "C" void kernel_launch(void* const* d_in, const int* in_sizes, int n_in,
                              void* d_out, int out_size, void* d_ws, size_t ws_size,
                              hipStream_t stream) {
    const float* ze  = (const float*)d_in[0];
    const float* emb = (const float*)d_in[1];
    const float* pd  = (const float*)d_in[2];
    const float* pu  = (const float*)d_in[3];
    const int*   nsp = (const int*)d_in[4];
    float* out = (float*)d_out;
    char* ws = (char*)d_ws;

    double* accum = (double*)(ws + OFF_ACC);
    double* en64  = (double*)(ws + OFF_EN64);
    float*  en32  = (float*)(ws + OFF_EN32);
    float*  pu_t  = (float*)(ws + OFF_PUT);
    double* r_ws  = (double*)(ws + OFF_R);
    float*  zq_ws = (float*)(ws + OFF_ZQ);

    hipMemsetAsync(accum, 0, 16, stream);
    knorm<<<(NPVQ * NRVQ * CBK + 255) / 256, 256, 0, stream>>>(emb, en64, en32);
    kputr<<<(NPVQ * CBD * HID + 255) / 256, 256, 0, stream>>>(pu, pu_t);
    kproj<<<NTOK / 2, 384, 0, stream>>>(ze, pd, r_ws);
    kvq<<<NPVQ * (NTOK / KV_TPB), KV_THREADS, 0, stream>>>(en64, en32, r_ws, zq_ws, out, nsp, accum);
    kout<<<NTOK / 32, 256, 0, stream>>>(pu_t, zq_ws, out, nsp, accum);
}